// Round 1
// baseline (670.584 us; speedup 1.0000x reference)
//
#include <hip/hip_runtime.h>
#include <hip/hip_bf16.h>
#include <math.h>

// Problem: B=64, T=1024, H=1024. M = B*T = 65536 score rows.
// out = [context (64*1024 fp32)] ++ [weights (64*1024 fp32)]
// ws fast path: [scores_p 16x64K f32 = 4MB][dec 256KB][W_bf16 2MB][A_bf16 128MB]

typedef __attribute__((ext_vector_type(8))) short bf16x8;
typedef __attribute__((ext_vector_type(8))) unsigned short ushort8;
typedef __attribute__((ext_vector_type(4))) float f32x4;

__device__ __forceinline__ unsigned short f2bf(float f) {
  union { float f; unsigned int u; } v; v.f = f;
  unsigned int r = v.u + 0x7FFFu + ((v.u >> 16) & 1u);  // RNE
  return (unsigned short)(r >> 16);
}

__device__ __forceinline__ float bf2f(unsigned short b) {
  union { unsigned int u; float f; } v; v.u = ((unsigned int)b) << 16;
  return v.f;
}

__device__ __forceinline__ float fast_tanh(float x) {
  float e = __expf(2.0f * x);
  return 1.0f - 2.0f / (e + 1.0f);  // saturates correctly at +-1
}

__device__ __forceinline__ void gld16(const void* g, void* l) {
  __builtin_amdgcn_global_load_lds(
      (const __attribute__((address_space(1))) void*)g,
      (__attribute__((address_space(3))) void*)l, 16, 0, 0);
}

// ===== fused prep kernel: W-cvt | A-cvt | dec-GEMV ============================
__global__ __launch_bounds__(256) void prep_kernel(
    const float* __restrict__ spatial, const float* __restrict__ hidden,
    const float* __restrict__ W_enc, const float* __restrict__ b_enc,
    const float* __restrict__ W_dec, const float* __restrict__ b_dec,
    unsigned short* __restrict__ Wbf, unsigned short* __restrict__ Abf,
    float* __restrict__ dec, int nW, int nA) {
  __shared__ float hs[1024];
  const int bid = blockIdx.x, tid = threadIdx.x;
  if (bid < nW + nA) {
    const float* src = (bid < nW) ? W_enc : spatial;
    unsigned short* dst = (bid < nW) ? Wbf : Abf;
    size_t g4 = (size_t)(bid < nW ? bid : bid - nW) * 256 + tid;
    float4 v = ((const float4*)src)[g4];
    ushort4 o;
    o.x = f2bf(v.x); o.y = f2bf(v.y); o.z = f2bf(v.z); o.w = f2bf(v.w);
    *(ushort4*)(dst + g4 * 4) = o;
    return;
  }
  const int dbid = bid - nW - nA;             // 0..511
  const int b = dbid >> 3, o0 = (dbid & 7) * 128;
  const int wave = tid >> 6, lane = tid & 63;
  ((float4*)hs)[tid] = ((const float4*)(hidden + (size_t)b * 1024))[tid];
  __syncthreads();
  for (int it = 0; it < 32; it++) {
    int o = o0 + it * 4 + wave;
    const float4* w4 = (const float4*)(W_dec + (size_t)o * 1024);
    float4 acc; acc.x = acc.y = acc.z = acc.w = 0.f;
    #pragma unroll
    for (int j = 0; j < 4; j++) {
      int i = j * 64 + lane;
      float4 x = ((const float4*)hs)[i], y = w4[i];
      acc.x = fmaf(x.x, y.x, acc.x);
      acc.y = fmaf(x.y, y.y, acc.y);
      acc.z = fmaf(x.z, y.z, acc.z);
      acc.w = fmaf(x.w, y.w, acc.w);
    }
    float v = (acc.x + acc.y) + (acc.z + acc.w);
    #pragma unroll
    for (int off = 1; off < 64; off <<= 1) v += __shfl_xor(v, off);
    if (lane == 0) dec[b * 1024 + o] = v + b_dec[o] + b_enc[o];
  }
}

// ======== FAST PATH: bf16 GEMM + tanh + w_score reduce ========================
// C[m,n] = sum_k A[m,k]*W[n,k]; tile 128x128, BK=64 (k-split-half LDS layout so
// bank-conflict + gld16 coalescing patterns match the proven BK=32 version,
// while halving barrier/drain count: 16 iters x 2 barriers, 32 MFMA/wave per
// iter). XCD-aware block swizzle: hw bids round-robin XCDs, so remap so each
// XCD owns a contiguous m-range with all 8 n-tiles -> the shared A m-tile
// stays in that XCD's private 4MB L2 (was a 4x HBM over-fetch, 530MB/disp).
// Score partials go to per-(ntile,wave-n-half) slots -> no atomics, no pre-zero.
__global__ __launch_bounds__(256) void enc_score_bf16_kernel(
    const unsigned short* __restrict__ A,   // bf16 bits [65536,1024]
    const unsigned short* __restrict__ W,   // bf16 bits [1024,1024]
    const float* __restrict__ dec,          // [64,1024] (b_dec+b_enc folded)
    const float* __restrict__ w_score,
    float* __restrict__ scores_p)           // [16][65536]
{
  __shared__ unsigned short As[2][128][32];   // 16 KB, k-half major
  __shared__ unsigned short Bs[2][128][32];   // 16 KB

  // XCD swizzle: grid 4096 = 8 * 512, bijective.
  const int bid = blockIdx.x;
  const int swz = (bid & 7) * 512 + (bid >> 3);
  const int n0 = (swz & 7) * 128;
  const int m0 = (swz >> 3) * 128;
  const int tid = threadIdx.x;
  const int lane = tid & 63, wave = tid >> 6;
  const int wm = (wave >> 1) * 64, wn = (wave & 1) * 64;
  const int quad = lane >> 4, colL = lane & 15;

  // staging: chunk (h, rg) = 1KB: rows [wave*32 + rg*16, +16) x k-cols
  // [k0 + h*32, +32). lane l -> row +(l>>2), col (l&3)*8. LDS dest is
  // wave-uniform base + lane*16B (gld16 contiguity requirement).
  const int srow = wave * 32 + (lane >> 2);
  const int scol = (lane & 3) * 8;
  const unsigned short* ga = A + (size_t)(m0 + srow) * 1024 + scol;
  const unsigned short* gb = W + (size_t)(n0 + srow) * 1024 + scol;
  unsigned short* la = &As[0][0][0] + wave * 1024;  // + h*4096 + rg*512
  unsigned short* lb = &Bs[0][0][0] + wave * 1024;

  f32x4 acc[4][4];
  #pragma unroll
  for (int mi = 0; mi < 4; mi++)
    #pragma unroll
    for (int ni = 0; ni < 4; ni++)
      acc[mi][ni] = (f32x4){0.f, 0.f, 0.f, 0.f};

  for (int k0 = 0; k0 < 1024; k0 += 64) {
    // A: 4 chunks (h in {0,32} global-k offset; rg in {0,16} row offset)
    gld16(ga + k0,                  la);
    gld16(ga + k0 + 16 * 1024,      la + 512);
    gld16(ga + k0 + 32,             la + 4096);
    gld16(ga + k0 + 32 + 16 * 1024, la + 4608);
    // B: 4 chunks
    gld16(gb + k0,                  lb);
    gld16(gb + k0 + 16 * 1024,      lb + 512);
    gld16(gb + k0 + 32,             lb + 4096);
    gld16(gb + k0 + 32 + 16 * 1024, lb + 4608);
    __syncthreads();
    #pragma unroll
    for (int h = 0; h < 2; h++) {
      bf16x8 af[4], bfr[4];
      #pragma unroll
      for (int i = 0; i < 4; i++) {
        af[i]  = *(const bf16x8*)(&As[h][wm + i * 16 + colL][quad * 8]);
        bfr[i] = *(const bf16x8*)(&Bs[h][wn + i * 16 + colL][quad * 8]);
      }
      #pragma unroll
      for (int mi = 0; mi < 4; mi++)
        #pragma unroll
        for (int ni = 0; ni < 4; ni++)
          acc[mi][ni] = __builtin_amdgcn_mfma_f32_16x16x32_bf16(
              af[mi], bfr[ni], acc[mi][ni], 0, 0, 0);
    }
    __syncthreads();
  }

  // epilogue: tanh(enc + dec') * w_score, reduce over this wave's 64 n's,
  // store into slot (n-tile, wave-n-half) -- non-atomic.
  const int b = m0 >> 10;
  float decv[4], wsv[4];
  #pragma unroll
  for (int ni = 0; ni < 4; ni++) {
    int n = n0 + wn + ni * 16 + colL;
    decv[ni] = dec[b * 1024 + n];
    wsv[ni] = w_score[n];
  }
  const int slot = (swz & 7) * 2 + (wave & 1);
  #pragma unroll
  for (int mi = 0; mi < 4; mi++) {
    float rs[4] = {0.f, 0.f, 0.f, 0.f};
    #pragma unroll
    for (int ni = 0; ni < 4; ni++)
      #pragma unroll
      for (int r = 0; r < 4; r++)
        rs[r] += fast_tanh(acc[mi][ni][r] + decv[ni]) * wsv[ni];
    #pragma unroll
    for (int r = 0; r < 4; r++) {
      float v = rs[r];
      v += __shfl_xor(v, 1);
      v += __shfl_xor(v, 2);
      v += __shfl_xor(v, 4);
      v += __shfl_xor(v, 8);
      if (colL == 0)
        scores_p[slot * 65536 + m0 + wm + mi * 16 + quad * 4 + r] = v;
    }
  }
}

// ======== FALLBACK (ws too small): fused fp32-staging GEMM ====================
__global__ __launch_bounds__(256) void enc_score_f32_kernel(
    const float* __restrict__ A, const float* __restrict__ W,
    const float* __restrict__ dec, const float* __restrict__ w_score,
    float* __restrict__ scores_p) {
  __shared__ unsigned short As[128][32];
  __shared__ unsigned short Bs[128][32];
  const int bid = blockIdx.x;
  const int n0 = (bid & 7) * 128;
  const int m0 = (bid >> 3) * 128;
  const int tid = threadIdx.x;
  const int lane = tid & 63, wave = tid >> 6;
  const int wm = (wave >> 1) * 64, wn = (wave & 1) * 64;
  const int quad = lane >> 4, colL = lane & 15;
  const int srow = tid >> 3;
  const int scol = (tid & 7) * 4;
  f32x4 acc[4][4];
  #pragma unroll
  for (int mi = 0; mi < 4; mi++)
    #pragma unroll
    for (int ni = 0; ni < 4; ni++)
      acc[mi][ni] = (f32x4){0.f, 0.f, 0.f, 0.f};
  for (int k0 = 0; k0 < 1024; k0 += 32) {
    #pragma unroll
    for (int p = 0; p < 4; p++) {
      int r = p * 32 + srow;
      float4 va = *(const float4*)(A + (size_t)(m0 + r) * 1024 + (k0 + scol));
      float4 vb = *(const float4*)(W + (size_t)(n0 + r) * 1024 + (k0 + scol));
      ushort4 pa, pb;
      pa.x = f2bf(va.x); pa.y = f2bf(va.y); pa.z = f2bf(va.z); pa.w = f2bf(va.w);
      pb.x = f2bf(vb.x); pb.y = f2bf(vb.y); pb.z = f2bf(vb.z); pb.w = f2bf(vb.w);
      *(ushort4*)(&As[r][scol]) = pa;
      *(ushort4*)(&Bs[r][scol]) = pb;
    }
    __syncthreads();
    bf16x8 af[4], bfr[4];
    #pragma unroll
    for (int i = 0; i < 4; i++) {
      af[i]  = *(const bf16x8*)(&As[wm + i * 16 + colL][quad * 8]);
      bfr[i] = *(const bf16x8*)(&Bs[wn + i * 16 + colL][quad * 8]);
    }
    #pragma unroll
    for (int mi = 0; mi < 4; mi++)
      #pragma unroll
      for (int ni = 0; ni < 4; ni++)
        acc[mi][ni] = __builtin_amdgcn_mfma_f32_16x16x32_bf16(
            af[mi], bfr[ni], acc[mi][ni], 0, 0, 0);
    __syncthreads();
  }
  const int b = m0 >> 10;
  float decv[4], wsv[4];
  #pragma unroll
  for (int ni = 0; ni < 4; ni++) {
    int n = n0 + wn + ni * 16 + colL;
    decv[ni] = dec[b * 1024 + n];
    wsv[ni] = w_score[n];
  }
  const int slot = (bid & 7) * 2 + (wave & 1);
  #pragma unroll
  for (int mi = 0; mi < 4; mi++) {
    float rsv[4] = {0.f, 0.f, 0.f, 0.f};
    #pragma unroll
    for (int ni = 0; ni < 4; ni++)
      #pragma unroll
      for (int r = 0; r < 4; r++)
        rsv[r] += fast_tanh(acc[mi][ni][r] + decv[ni]) * wsv[ni];
    #pragma unroll
    for (int r = 0; r < 4; r++) {
      float v = rsv[r];
      v += __shfl_xor(v, 1);
      v += __shfl_xor(v, 2);
      v += __shfl_xor(v, 4);
      v += __shfl_xor(v, 8);
      if (colL == 0)
        scores_p[slot * 65536 + m0 + wm + mi * 16 + quad * 4 + r] = v;
    }
  }
}

// ------- softmax over T per batch; sums 16 partial slots; zeros context -------
__global__ void softmax_kernel(const float* __restrict__ scores_p,
                               float* __restrict__ weights,
                               float* __restrict__ context) {
  __shared__ float red[256];
  int b = blockIdx.x, tid = threadIdx.x;
  float4 z; z.x = z.y = z.z = z.w = 0.f;
  ((float4*)context)[blockIdx.x * 256 + tid] = z;
  float v[4];
  float mx = -1e30f;
  #pragma unroll
  for (int i = 0; i < 4; i++) {
    int m = b * 1024 + tid + i * 256;
    float s = 0.f;
    #pragma unroll
    for (int sl = 0; sl < 16; sl++) s += scores_p[sl * 65536 + m];
    v[i] = s;
    mx = fmaxf(mx, v[i]);
  }
  red[tid] = mx; __syncthreads();
  for (int off = 128; off > 0; off >>= 1) {
    if (tid < off) red[tid] = fmaxf(red[tid], red[tid + off]);
    __syncthreads();
  }
  mx = red[0]; __syncthreads();
  float sum = 0.f;
  #pragma unroll
  for (int i = 0; i < 4; i++) { v[i] = __expf(v[i] - mx); sum += v[i]; }
  red[tid] = sum; __syncthreads();
  for (int off = 128; off > 0; off >>= 1) {
    if (tid < off) red[tid] += red[tid + off];
    __syncthreads();
  }
  float inv = 1.0f / red[0];
  #pragma unroll
  for (int i = 0; i < 4; i++) weights[b * 1024 + tid + i * 256] = v[i] * inv;
}

// -------- context[b,h] = sum_t spatial[b,t,h] * weights[b,t]  (bf16 A) --------
__global__ void context_bf16_kernel(const unsigned short* __restrict__ Abf,
                                    const float* __restrict__ weights,
                                    float* __restrict__ context) {
  int b = blockIdx.x >> 3, tq = blockIdx.x & 7;
  int tid = threadIdx.x;
  __shared__ float wl[128];
  __shared__ float cs[128 * 8];
  if (tid < 128) wl[tid] = weights[b * 1024 + tq * 128 + tid];
  __syncthreads();
  const int hl = tid & 127, p = tid >> 7;   // 128 h-groups x 2 row parities
  const int h0 = hl * 8;
  const unsigned short* sp =
      Abf + ((size_t)(b * 1024 + tq * 128 + p)) * 1024 + h0;
  float acc[8];
  #pragma unroll
  for (int j = 0; j < 8; j++) acc[j] = 0.f;
  for (int t = 0; t < 128; t += 2) {
    float w = wl[t + p];
    ushort8 x = *(const ushort8*)(sp + (size_t)t * 1024);
    #pragma unroll
    for (int j = 0; j < 8; j++) acc[j] = fmaf(w, bf2f(x[j]), acc[j]);
  }
  if (p == 0) {
    #pragma unroll
    for (int j = 0; j < 8; j++) cs[hl * 8 + j] = acc[j];
  }
  __syncthreads();
  if (p == 1) {
    #pragma unroll
    for (int j = 0; j < 8; j++) cs[hl * 8 + j] += acc[j];
  }
  __syncthreads();
  if (p == 0) {
    #pragma unroll
    for (int j = 0; j < 8; j++)
      atomicAdd(&context[b * 1024 + h0 + j], cs[hl * 8 + j]);
  }
}

// fp32 context for fallback path
__global__ void context_f32_kernel(const float* __restrict__ spatial,
                                   const float* __restrict__ weights,
                                   float* __restrict__ context) {
  int b = blockIdx.x >> 3, tq = blockIdx.x & 7;
  int tid = threadIdx.x;
  __shared__ float wl[128];
  if (tid < 128) wl[tid] = weights[b * 1024 + tq * 128 + tid];
  __syncthreads();
  const float4* sp =
      (const float4*)(spatial + ((size_t)(b * 1024 + tq * 128)) * 1024);
  float4 acc; acc.x = acc.y = acc.z = acc.w = 0.f;
  #pragma unroll 4
  for (int t = 0; t < 128; t++) {
    float w = wl[t];
    float4 x = sp[(size_t)t * 256 + tid];
    acc.x = fmaf(w, x.x, acc.x);
    acc.y = fmaf(w, x.y, acc.y);
    acc.z = fmaf(w, x.z, acc.z);
    acc.w = fmaf(w, x.w, acc.w);
  }
  float* c = context + b * 1024 + tid * 4;
  atomicAdd(c + 0, acc.x);
  atomicAdd(c + 1, acc.y);
  atomicAdd(c + 2, acc.z);
  atomicAdd(c + 3, acc.w);
}

extern "C" void kernel_launch(void* const* d_in, const int* in_sizes, int n_in,
                              void* d_out, int out_size, void* d_ws, size_t ws_size,
                              hipStream_t stream) {
  const float* spatial  = (const float*)d_in[0];  // [64,1024,1024]
  const float* hidden   = (const float*)d_in[1];  // [64,1024]
  const float* W_enc    = (const float*)d_in[2];  // [1024,1024]
  const float* b_enc    = (const float*)d_in[3];  // [1024]
  const float* W_dec    = (const float*)d_in[4];  // [1024,1024]
  const float* b_dec    = (const float*)d_in[5];  // [1024]
  const float* w_score  = (const float*)d_in[6];  // [1024]
  // d_in[7] = b_score: softmax shift-invariant, unused.

  float* out      = (float*)d_out;
  float* context  = out;            // 65536 floats
  float* weights  = out + 65536;    // 65536 floats

  float* scores_p = (float*)d_ws;                            // 16*64K f32 @ 0
  float* dec      = scores_p + 16 * 65536;                   // 64K f32 @ 4MB
  unsigned short* Wbf = (unsigned short*)(dec + 65536);      // 1M  @ 4.25MB
  unsigned short* Abf = Wbf + 1024 * 1024;                   // 64M @ 6.25MB

  const size_t need =
      16ull * 65536 * 4 + 65536 * 4 + 2ull * 1024 * 1024 + 2ull * 65536 * 1024;

  if (ws_size >= need) {
    const int nW = 1024, nA = 65536;
    prep_kernel<<<nW + nA + 512, 256, 0, stream>>>(
        spatial, hidden, W_enc, b_enc, W_dec, b_dec, Wbf, Abf, dec, nW, nA);
    enc_score_bf16_kernel<<<4096, 256, 0, stream>>>(Abf, Wbf, dec, w_score,
                                                    scores_p);
    softmax_kernel<<<64, 256, 0, stream>>>(scores_p, weights, context);
    context_bf16_kernel<<<512, 256, 0, stream>>>(Abf, weights, context);
  } else {
    prep_kernel<<<512, 256, 0, stream>>>(
        spatial, hidden, W_enc, b_enc, W_dec, b_dec, nullptr, nullptr, dec,
        0, 0);
    enc_score_f32_kernel<<<4096, 256, 0, stream>>>(spatial, W_enc, dec,
                                                   w_score, scores_p);
    softmax_kernel<<<64, 256, 0, stream>>>(scores_p, weights, context);
    context_f32_kernel<<<512, 256, 0, stream>>>(spatial, weights, context);
  }
}

// Round 2
// 654.360 us; speedup vs baseline: 1.0248x; 1.0248x over previous
//
#include <hip/hip_runtime.h>
#include <hip/hip_bf16.h>
#include <math.h>

// Problem: B=64, T=1024, H=1024. M = B*T = 65536 score rows.
// out = [context (64*1024 fp32)] ++ [weights (64*1024 fp32)]
// ws fast path: [scores_p 16x64K f32 = 4MB][dec 256KB][W_bf16 2MB][A_bf16 128MB]

typedef __attribute__((ext_vector_type(8))) short bf16x8;
typedef __attribute__((ext_vector_type(8))) unsigned short ushort8;
typedef __attribute__((ext_vector_type(4))) float f32x4;

__device__ __forceinline__ unsigned short f2bf(float f) {
  union { float f; unsigned int u; } v; v.f = f;
  unsigned int r = v.u + 0x7FFFu + ((v.u >> 16) & 1u);  // RNE
  return (unsigned short)(r >> 16);
}

__device__ __forceinline__ float bf2f(unsigned short b) {
  union { unsigned int u; float f; } v; v.u = ((unsigned int)b) << 16;
  return v.f;
}

__device__ __forceinline__ float fast_tanh(float x) {
  float e = __expf(2.0f * x);
  return 1.0f - 2.0f / (e + 1.0f);  // saturates correctly at +-1
}

__device__ __forceinline__ void gld16(const void* g, void* l) {
  __builtin_amdgcn_global_load_lds(
      (const __attribute__((address_space(1))) void*)g,
      (__attribute__((address_space(3))) void*)l, 16, 0, 0);
}

// ===== fused prep kernel: W-cvt | A-cvt | dec-GEMV ============================
// cvt part grid-strided: 32 W-blocks + 2048 A-blocks, 32 float4/thread each
// (was 66560 one-load blocks -> dispatch overhead). dec-GEMV part unchanged.
__global__ __launch_bounds__(256) void prep_kernel(
    const float* __restrict__ spatial, const float* __restrict__ hidden,
    const float* __restrict__ W_enc, const float* __restrict__ b_enc,
    const float* __restrict__ W_dec, const float* __restrict__ b_dec,
    unsigned short* __restrict__ Wbf, unsigned short* __restrict__ Abf,
    float* __restrict__ dec, int nCvt) {
  __shared__ float hs[1024];
  const int bid = blockIdx.x, tid = threadIdx.x;
  if (bid < nCvt) {
    const bool isW = bid < 32;                 // W: 262144 float4 = 32 blocks
    const float* src = isW ? W_enc : spatial;  // A: 16M float4 = 2048 blocks
    unsigned short* dst = isW ? Wbf : Abf;
    const size_t base = (size_t)(isW ? bid : bid - 32) * 8192 + tid;
    #pragma unroll 4
    for (int i = 0; i < 32; i++) {
      size_t g4 = base + (size_t)i * 256;
      float4 v = ((const float4*)src)[g4];
      ushort4 o;
      o.x = f2bf(v.x); o.y = f2bf(v.y); o.z = f2bf(v.z); o.w = f2bf(v.w);
      *(ushort4*)(dst + g4 * 4) = o;
    }
    return;
  }
  const int dbid = bid - nCvt;                // 0..511
  const int b = dbid >> 3, o0 = (dbid & 7) * 128;
  const int wave = tid >> 6, lane = tid & 63;
  ((float4*)hs)[tid] = ((const float4*)(hidden + (size_t)b * 1024))[tid];
  __syncthreads();
  for (int it = 0; it < 32; it++) {
    int o = o0 + it * 4 + wave;
    const float4* w4 = (const float4*)(W_dec + (size_t)o * 1024);
    float4 acc; acc.x = acc.y = acc.z = acc.w = 0.f;
    #pragma unroll
    for (int j = 0; j < 4; j++) {
      int i = j * 64 + lane;
      float4 x = ((const float4*)hs)[i], y = w4[i];
      acc.x = fmaf(x.x, y.x, acc.x);
      acc.y = fmaf(x.y, y.y, acc.y);
      acc.z = fmaf(x.z, y.z, acc.z);
      acc.w = fmaf(x.w, y.w, acc.w);
    }
    float v = (acc.x + acc.y) + (acc.z + acc.w);
    #pragma unroll
    for (int off = 1; off < 64; off <<= 1) v += __shfl_xor(v, off);
    if (lane == 0) dec[b * 1024 + o] = v + b_dec[o] + b_enc[o];
  }
}

// ======== FAST PATH: bf16 GEMM + tanh + w_score reduce ========================
// C[m,n] = sum_k A[m,k]*W[n,k]; tile 128x128, BK=32 (proven r0 layout), 4 waves.
// T3/T4 pipeline: 3 LDS buffers, 2 K-tiles staged ahead, counted
// s_waitcnt vmcnt(4) + raw s_barrier -- ONE barrier per K-tile and never a
// full vmcnt(0) drain in the main loop (epilogue-only). T1 XCD swizzle kept
// (fetch 530->79MB proven r1); T5 setprio around MFMA cluster.
__global__ __launch_bounds__(256) void enc_score_bf16_kernel(
    const unsigned short* __restrict__ A,   // bf16 bits [65536,1024]
    const unsigned short* __restrict__ W,   // bf16 bits [1024,1024]
    const float* __restrict__ dec,          // [64,1024] (b_dec+b_enc folded)
    const float* __restrict__ w_score,
    float* __restrict__ scores_p)           // [16][65536]
{
  __shared__ unsigned short As[3][128][32];   // 24 KB
  __shared__ unsigned short Bs[3][128][32];   // 24 KB

  // XCD swizzle: grid 4096 = 8 * 512, bijective.
  const int bid = blockIdx.x;
  const int swz = (bid & 7) * 512 + (bid >> 3);
  const int n0 = (swz & 7) * 128;
  const int m0 = (swz >> 3) * 128;
  const int tid = threadIdx.x;
  const int lane = tid & 63, wave = tid >> 6;
  const int wm = (wave >> 1) * 64, wn = (wave & 1) * 64;
  const int quad = lane >> 4, colL = lane & 15;

  // staging: wave covers rows [wave*32, +32); lane l -> row +(l>>2),
  // col (l&3)*8. LDS dest = wave-uniform base + lane*16B (gld16 rule).
  const int srow = wave * 32 + (lane >> 2);
  const int scol = (lane & 3) * 8;
  const unsigned short* ga = A + (size_t)(m0 + srow) * 1024 + scol;
  const unsigned short* gb = W + (size_t)(n0 + srow) * 1024 + scol;
  unsigned short* la = &As[0][0][0] + wave * 1024;
  unsigned short* lb = &Bs[0][0][0] + wave * 1024;

  f32x4 acc[4][4];
  #pragma unroll
  for (int mi = 0; mi < 4; mi++)
    #pragma unroll
    for (int ni = 0; ni < 4; ni++)
      acc[mi][ni] = (f32x4){0.f, 0.f, 0.f, 0.f};

  // 4 gld16 per thread per K-tile (2 A chunks + 2 B chunks).
  auto stage_tile = [&](int t, int b) {
    const unsigned short* ga_ = ga + t * 32;
    const unsigned short* gb_ = gb + t * 32;
    unsigned short* la_ = la + b * 4096;
    unsigned short* lb_ = lb + b * 4096;
    gld16(ga_,             la_);
    gld16(ga_ + 16 * 1024, la_ + 512);
    gld16(gb_,             lb_);
    gld16(gb_ + 16 * 1024, lb_ + 512);
  };

  auto compute_tile = [&](int b) {
    bf16x8 af[4], bfr[4];
    #pragma unroll
    for (int i = 0; i < 4; i++) {
      af[i]  = *(const bf16x8*)(&As[b][wm + i * 16 + colL][quad * 8]);
      bfr[i] = *(const bf16x8*)(&Bs[b][wn + i * 16 + colL][quad * 8]);
    }
    __builtin_amdgcn_s_setprio(1);
    #pragma unroll
    for (int mi = 0; mi < 4; mi++)
      #pragma unroll
      for (int ni = 0; ni < 4; ni++)
        acc[mi][ni] = __builtin_amdgcn_mfma_f32_16x16x32_bf16(
            af[mi], bfr[ni], acc[mi][ni], 0, 0, 0);
    __builtin_amdgcn_s_setprio(0);
  };

  // prologue: tiles 0,1 in flight
  stage_tile(0, 0);
  stage_tile(1, 1);

  int buf = 0;
  for (int t = 0; t < 31; t++) {
    // own-wave tile-t loads done (tile t+1 may remain in flight: 4 loads)
    asm volatile("s_waitcnt vmcnt(4)" ::: "memory");
    // all waves have tile t staged; all waves done computing tile t-1,
    // so buf (t+2)%3 (= (t-1)%3) is free to overwrite.
    __builtin_amdgcn_s_barrier();
    if (t < 30) {
      int b2 = buf + 2; if (b2 >= 3) b2 -= 3;
      stage_tile(t + 2, b2);
    }
    compute_tile(buf);
    buf = (buf == 2) ? 0 : buf + 1;
  }
  asm volatile("s_waitcnt vmcnt(0)" ::: "memory");
  __builtin_amdgcn_s_barrier();
  compute_tile(buf);   // tile 31, buf 1

  // epilogue: tanh(enc + dec') * w_score, reduce over this wave's 64 n's,
  // store into slot (n-tile, wave-n-half) -- non-atomic.
  const int b = m0 >> 10;
  float decv[4], wsv[4];
  #pragma unroll
  for (int ni = 0; ni < 4; ni++) {
    int n = n0 + wn + ni * 16 + colL;
    decv[ni] = dec[b * 1024 + n];
    wsv[ni] = w_score[n];
  }
  const int slot = (swz & 7) * 2 + (wave & 1);
  #pragma unroll
  for (int mi = 0; mi < 4; mi++) {
    float rs[4] = {0.f, 0.f, 0.f, 0.f};
    #pragma unroll
    for (int ni = 0; ni < 4; ni++)
      #pragma unroll
      for (int r = 0; r < 4; r++)
        rs[r] += fast_tanh(acc[mi][ni][r] + decv[ni]) * wsv[ni];
    #pragma unroll
    for (int r = 0; r < 4; r++) {
      float v = rs[r];
      v += __shfl_xor(v, 1);
      v += __shfl_xor(v, 2);
      v += __shfl_xor(v, 4);
      v += __shfl_xor(v, 8);
      if (colL == 0)
        scores_p[slot * 65536 + m0 + wm + mi * 16 + quad * 4 + r] = v;
    }
  }
}

// ======== FALLBACK (ws too small): fused fp32-staging GEMM ====================
__global__ __launch_bounds__(256) void enc_score_f32_kernel(
    const float* __restrict__ A, const float* __restrict__ W,
    const float* __restrict__ dec, const float* __restrict__ w_score,
    float* __restrict__ scores_p) {
  __shared__ unsigned short As[128][32];
  __shared__ unsigned short Bs[128][32];
  const int bid = blockIdx.x;
  const int n0 = (bid & 7) * 128;
  const int m0 = (bid >> 3) * 128;
  const int tid = threadIdx.x;
  const int lane = tid & 63, wave = tid >> 6;
  const int wm = (wave >> 1) * 64, wn = (wave & 1) * 64;
  const int quad = lane >> 4, colL = lane & 15;
  const int srow = tid >> 3;
  const int scol = (tid & 7) * 4;
  f32x4 acc[4][4];
  #pragma unroll
  for (int mi = 0; mi < 4; mi++)
    #pragma unroll
    for (int ni = 0; ni < 4; ni++)
      acc[mi][ni] = (f32x4){0.f, 0.f, 0.f, 0.f};
  for (int k0 = 0; k0 < 1024; k0 += 32) {
    #pragma unroll
    for (int p = 0; p < 4; p++) {
      int r = p * 32 + srow;
      float4 va = *(const float4*)(A + (size_t)(m0 + r) * 1024 + (k0 + scol));
      float4 vb = *(const float4*)(W + (size_t)(n0 + r) * 1024 + (k0 + scol));
      ushort4 pa, pb;
      pa.x = f2bf(va.x); pa.y = f2bf(va.y); pa.z = f2bf(va.z); pa.w = f2bf(va.w);
      pb.x = f2bf(vb.x); pb.y = f2bf(vb.y); pb.z = f2bf(vb.z); pb.w = f2bf(vb.w);
      *(ushort4*)(&As[r][scol]) = pa;
      *(ushort4*)(&Bs[r][scol]) = pb;
    }
    __syncthreads();
    bf16x8 af[4], bfr[4];
    #pragma unroll
    for (int i = 0; i < 4; i++) {
      af[i]  = *(const bf16x8*)(&As[wm + i * 16 + colL][quad * 8]);
      bfr[i] = *(const bf16x8*)(&Bs[wn + i * 16 + colL][quad * 8]);
    }
    #pragma unroll
    for (int mi = 0; mi < 4; mi++)
      #pragma unroll
      for (int ni = 0; ni < 4; ni++)
        acc[mi][ni] = __builtin_amdgcn_mfma_f32_16x16x32_bf16(
            af[mi], bfr[ni], acc[mi][ni], 0, 0, 0);
    __syncthreads();
  }
  const int b = m0 >> 10;
  float decv[4], wsv[4];
  #pragma unroll
  for (int ni = 0; ni < 4; ni++) {
    int n = n0 + wn + ni * 16 + colL;
    decv[ni] = dec[b * 1024 + n];
    wsv[ni] = w_score[n];
  }
  const int slot = (bid & 7) * 2 + (wave & 1);
  #pragma unroll
  for (int mi = 0; mi < 4; mi++) {
    float rsv[4] = {0.f, 0.f, 0.f, 0.f};
    #pragma unroll
    for (int ni = 0; ni < 4; ni++)
      #pragma unroll
      for (int r = 0; r < 4; r++)
        rsv[r] += fast_tanh(acc[mi][ni][r] + decv[ni]) * wsv[ni];
    #pragma unroll
    for (int r = 0; r < 4; r++) {
      float v = rsv[r];
      v += __shfl_xor(v, 1);
      v += __shfl_xor(v, 2);
      v += __shfl_xor(v, 4);
      v += __shfl_xor(v, 8);
      if (colL == 0)
        scores_p[slot * 65536 + m0 + wm + mi * 16 + quad * 4 + r] = v;
    }
  }
}

// ------- softmax over T per batch; sums 16 partial slots; zeros context -------
__global__ void softmax_kernel(const float* __restrict__ scores_p,
                               float* __restrict__ weights,
                               float* __restrict__ context) {
  __shared__ float red[256];
  int b = blockIdx.x, tid = threadIdx.x;
  float4 z; z.x = z.y = z.z = z.w = 0.f;
  ((float4*)context)[blockIdx.x * 256 + tid] = z;
  float v[4];
  float mx = -1e30f;
  #pragma unroll
  for (int i = 0; i < 4; i++) {
    int m = b * 1024 + tid + i * 256;
    float s = 0.f;
    #pragma unroll
    for (int sl = 0; sl < 16; sl++) s += scores_p[sl * 65536 + m];
    v[i] = s;
    mx = fmaxf(mx, v[i]);
  }
  red[tid] = mx; __syncthreads();
  for (int off = 128; off > 0; off >>= 1) {
    if (tid < off) red[tid] = fmaxf(red[tid], red[tid + off]);
    __syncthreads();
  }
  mx = red[0]; __syncthreads();
  float sum = 0.f;
  #pragma unroll
  for (int i = 0; i < 4; i++) { v[i] = __expf(v[i] - mx); sum += v[i]; }
  red[tid] = sum; __syncthreads();
  for (int off = 128; off > 0; off >>= 1) {
    if (tid < off) red[tid] += red[tid + off];
    __syncthreads();
  }
  float inv = 1.0f / red[0];
  #pragma unroll
  for (int i = 0; i < 4; i++) weights[b * 1024 + tid + i * 256] = v[i] * inv;
}

// -------- context[b,h] = sum_t spatial[b,t,h] * weights[b,t]  (bf16 A) --------
__global__ void context_bf16_kernel(const unsigned short* __restrict__ Abf,
                                    const float* __restrict__ weights,
                                    float* __restrict__ context) {
  int b = blockIdx.x >> 3, tq = blockIdx.x & 7;
  int tid = threadIdx.x;
  __shared__ float wl[128];
  __shared__ float cs[128 * 8];
  if (tid < 128) wl[tid] = weights[b * 1024 + tq * 128 + tid];
  __syncthreads();
  const int hl = tid & 127, p = tid >> 7;   // 128 h-groups x 2 row parities
  const int h0 = hl * 8;
  const unsigned short* sp =
      Abf + ((size_t)(b * 1024 + tq * 128 + p)) * 1024 + h0;
  float acc[8];
  #pragma unroll
  for (int j = 0; j < 8; j++) acc[j] = 0.f;
  for (int t = 0; t < 128; t += 2) {
    float w = wl[t + p];
    ushort8 x = *(const ushort8*)(sp + (size_t)t * 1024);
    #pragma unroll
    for (int j = 0; j < 8; j++) acc[j] = fmaf(w, bf2f(x[j]), acc[j]);
  }
  if (p == 0) {
    #pragma unroll
    for (int j = 0; j < 8; j++) cs[hl * 8 + j] = acc[j];
  }
  __syncthreads();
  if (p == 1) {
    #pragma unroll
    for (int j = 0; j < 8; j++) cs[hl * 8 + j] += acc[j];
  }
  __syncthreads();
  if (p == 0) {
    #pragma unroll
    for (int j = 0; j < 8; j++)
      atomicAdd(&context[b * 1024 + h0 + j], cs[hl * 8 + j]);
  }
}

// fp32 context for fallback path
__global__ void context_f32_kernel(const float* __restrict__ spatial,
                                   const float* __restrict__ weights,
                                   float* __restrict__ context) {
  int b = blockIdx.x >> 3, tq = blockIdx.x & 7;
  int tid = threadIdx.x;
  __shared__ float wl[128];
  if (tid < 128) wl[tid] = weights[b * 1024 + tq * 128 + tid];
  __syncthreads();
  const float4* sp =
      (const float4*)(spatial + ((size_t)(b * 1024 + tq * 128)) * 1024);
  float4 acc; acc.x = acc.y = acc.z = acc.w = 0.f;
  #pragma unroll 4
  for (int t = 0; t < 128; t++) {
    float w = wl[t];
    float4 x = sp[(size_t)t * 256 + tid];
    acc.x = fmaf(w, x.x, acc.x);
    acc.y = fmaf(w, x.y, acc.y);
    acc.z = fmaf(w, x.z, acc.z);
    acc.w = fmaf(w, x.w, acc.w);
  }
  float* c = context + b * 1024 + tid * 4;
  atomicAdd(c + 0, acc.x);
  atomicAdd(c + 1, acc.y);
  atomicAdd(c + 2, acc.z);
  atomicAdd(c + 3, acc.w);
}

extern "C" void kernel_launch(void* const* d_in, const int* in_sizes, int n_in,
                              void* d_out, int out_size, void* d_ws, size_t ws_size,
                              hipStream_t stream) {
  const float* spatial  = (const float*)d_in[0];  // [64,1024,1024]
  const float* hidden   = (const float*)d_in[1];  // [64,1024]
  const float* W_enc    = (const float*)d_in[2];  // [1024,1024]
  const float* b_enc    = (const float*)d_in[3];  // [1024]
  const float* W_dec    = (const float*)d_in[4];  // [1024,1024]
  const float* b_dec    = (const float*)d_in[5];  // [1024]
  const float* w_score  = (const float*)d_in[6];  // [1024]
  // d_in[7] = b_score: softmax shift-invariant, unused.

  float* out      = (float*)d_out;
  float* context  = out;            // 65536 floats
  float* weights  = out + 65536;    // 65536 floats

  float* scores_p = (float*)d_ws;                            // 16*64K f32 @ 0
  float* dec      = scores_p + 16 * 65536;                   // 64K f32 @ 4MB
  unsigned short* Wbf = (unsigned short*)(dec + 65536);      // 1M  @ 4.25MB
  unsigned short* Abf = Wbf + 1024 * 1024;                   // 64M @ 6.25MB

  const size_t need =
      16ull * 65536 * 4 + 65536 * 4 + 2ull * 1024 * 1024 + 2ull * 65536 * 1024;

  if (ws_size >= need) {
    const int nCvt = 32 + 2048;   // W blocks + A blocks (8192 float4 each)
    prep_kernel<<<nCvt + 512, 256, 0, stream>>>(
        spatial, hidden, W_enc, b_enc, W_dec, b_dec, Wbf, Abf, dec, nCvt);
    enc_score_bf16_kernel<<<4096, 256, 0, stream>>>(Abf, Wbf, dec, w_score,
                                                    scores_p);
    softmax_kernel<<<64, 256, 0, stream>>>(scores_p, weights, context);
    context_bf16_kernel<<<512, 256, 0, stream>>>(Abf, weights, context);
  } else {
    prep_kernel<<<512, 256, 0, stream>>>(
        spatial, hidden, W_enc, b_enc, W_dec, b_dec, nullptr, nullptr, dec,
        0);
    enc_score_f32_kernel<<<4096, 256, 0, stream>>>(spatial, W_enc, dec,
                                                   w_score, scores_p);
    softmax_kernel<<<64, 256, 0, stream>>>(scores_p, weights, context);
    context_f32_kernel<<<512, 256, 0, stream>>>(spatial, weights, context);
  }
}

// Round 3
// 647.219 us; speedup vs baseline: 1.0361x; 1.0110x over previous
//
#include <hip/hip_runtime.h>
#include <hip/hip_bf16.h>
#include <math.h>

// Problem: B=64, T=1024, H=1024. M = B*T = 65536 score rows.
// out = [context (64*1024 fp32)] ++ [weights (64*1024 fp32)]
// ws fast path: [scores_p 16x64K f32 = 4MB][dec 256KB][W_bf16 2MB][A_bf16 128MB]

typedef __attribute__((ext_vector_type(8))) short bf16x8;
typedef __attribute__((ext_vector_type(8))) unsigned short ushort8;
typedef __attribute__((ext_vector_type(4))) float f32x4;

__device__ __forceinline__ unsigned short f2bf(float f) {
  union { float f; unsigned int u; } v; v.f = f;
  unsigned int r = v.u + 0x7FFFu + ((v.u >> 16) & 1u);  // RNE
  return (unsigned short)(r >> 16);
}

__device__ __forceinline__ float bf2f(unsigned short b) {
  union { unsigned int u; float f; } v; v.u = ((unsigned int)b) << 16;
  return v.f;
}

__device__ __forceinline__ float fast_tanh(float x) {
  float e = __expf(2.0f * x);
  return 1.0f - 2.0f / (e + 1.0f);  // saturates correctly at +-1
}

__device__ __forceinline__ void gld16(const void* g, void* l) {
  __builtin_amdgcn_global_load_lds(
      (const __attribute__((address_space(1))) void*)g,
      (__attribute__((address_space(3))) void*)l, 16, 0, 0);
}

// ===== fused prep kernel: W-cvt | A-cvt | dec-GEMV ============================
// cvt part grid-strided: 32 W-blocks + 2048 A-blocks, 32 float4/thread each.
__global__ __launch_bounds__(256) void prep_kernel(
    const float* __restrict__ spatial, const float* __restrict__ hidden,
    const float* __restrict__ W_enc, const float* __restrict__ b_enc,
    const float* __restrict__ W_dec, const float* __restrict__ b_dec,
    unsigned short* __restrict__ Wbf, unsigned short* __restrict__ Abf,
    float* __restrict__ dec, int nCvt) {
  __shared__ float hs[1024];
  const int bid = blockIdx.x, tid = threadIdx.x;
  if (bid < nCvt) {
    const bool isW = bid < 32;                 // W: 262144 float4 = 32 blocks
    const float* src = isW ? W_enc : spatial;  // A: 16M float4 = 2048 blocks
    unsigned short* dst = isW ? Wbf : Abf;
    const size_t base = (size_t)(isW ? bid : bid - 32) * 8192 + tid;
    #pragma unroll 4
    for (int i = 0; i < 32; i++) {
      size_t g4 = base + (size_t)i * 256;
      float4 v = ((const float4*)src)[g4];
      ushort4 o;
      o.x = f2bf(v.x); o.y = f2bf(v.y); o.z = f2bf(v.z); o.w = f2bf(v.w);
      *(ushort4*)(dst + g4 * 4) = o;
    }
    return;
  }
  const int dbid = bid - nCvt;                // 0..511
  const int b = dbid >> 3, o0 = (dbid & 7) * 128;
  const int wave = tid >> 6, lane = tid & 63;
  ((float4*)hs)[tid] = ((const float4*)(hidden + (size_t)b * 1024))[tid];
  __syncthreads();
  for (int it = 0; it < 32; it++) {
    int o = o0 + it * 4 + wave;
    const float4* w4 = (const float4*)(W_dec + (size_t)o * 1024);
    float4 acc; acc.x = acc.y = acc.z = acc.w = 0.f;
    #pragma unroll
    for (int j = 0; j < 4; j++) {
      int i = j * 64 + lane;
      float4 x = ((const float4*)hs)[i], y = w4[i];
      acc.x = fmaf(x.x, y.x, acc.x);
      acc.y = fmaf(x.y, y.y, acc.y);
      acc.z = fmaf(x.z, y.z, acc.z);
      acc.w = fmaf(x.w, y.w, acc.w);
    }
    float v = (acc.x + acc.y) + (acc.z + acc.w);
    #pragma unroll
    for (int off = 1; off < 64; off <<= 1) v += __shfl_xor(v, off);
    if (lane == 0) dec[b * 1024 + o] = v + b_dec[o] + b_enc[o];
  }
}

// ======== FAST PATH: bf16 GEMM + tanh + w_score reduce ========================
// C[m,n] = sum_k A[m,k]*W[n,k]; tile 128x128, BK=32, 4 waves (2x2 of 64x64).
// T3/T4 pipeline (r2): 3 LDS buffers, 2 K-tiles ahead, counted vmcnt(4) +
// raw s_barrier, no vmcnt(0) drain in main loop. T1 XCD swizzle (r1: fetch
// 530->79MB). NEW r3 = T2 bank-conflict fix, gld16-compatible (rule 21):
// LDS dest stays linear; the GLOBAL source col-block is pre-permuted by
// c ^= (row>>1)&3 (16B granularity), and fragment reads apply the same XOR.
// Naive layout had byte = row*64 + quad*16 -> 8 even-colL lanes on one 4-bank
// group = 8-way conflict (the constant 1.678e7 SQ_LDS_BANK_CONFLICT). With
// (row>>1)&3 the 16 same-quad lanes spread over all 8 bank groups -> 2-way,
// which is free (m136).
__global__ __launch_bounds__(256) void enc_score_bf16_kernel(
    const unsigned short* __restrict__ A,   // bf16 bits [65536,1024]
    const unsigned short* __restrict__ W,   // bf16 bits [1024,1024]
    const float* __restrict__ dec,          // [64,1024] (b_dec+b_enc folded)
    const float* __restrict__ w_score,
    float* __restrict__ scores_p)           // [16][65536]
{
  __shared__ unsigned short As[3][128][32];   // 24 KB
  __shared__ unsigned short Bs[3][128][32];   // 24 KB

  // XCD swizzle: grid 4096 = 8 * 512, bijective.
  const int bid = blockIdx.x;
  const int swz = (bid & 7) * 512 + (bid >> 3);
  const int n0 = (swz & 7) * 128;
  const int m0 = (swz >> 3) * 128;
  const int tid = threadIdx.x;
  const int lane = tid & 63, wave = tid >> 6;
  const int wm = (wave >> 1) * 64, wn = (wave & 1) * 64;
  const int quad = lane >> 4, colL = lane & 15;

  // staging: wave covers rows [wave*32, +32); lane l -> row +(l>>2).
  // LDS dest = wave-uniform base + lane*16B (linear, gld16 rule). The col
  // block this lane FETCHES is XOR-permuted so LDS[row][c] holds global
  // block c ^ ((row>>1)&3). (l>>3)&3 == ((lds_row)>>1)&3 for both 16-row
  // chunks since chunk offset 16 and wave offset 32 vanish mod 4 after >>1.
  const int srow = wave * 32 + (lane >> 2);
  const int scol = (((lane & 3) ^ ((lane >> 3) & 3)) * 8);
  const unsigned short* ga = A + (size_t)(m0 + srow) * 1024 + scol;
  const unsigned short* gb = W + (size_t)(n0 + srow) * 1024 + scol;
  unsigned short* la = &As[0][0][0] + wave * 1024;
  unsigned short* lb = &Bs[0][0][0] + wave * 1024;

  // fragment-read col slot: quad ^ ((row>>1)&3); row = wm|wn + i*16 + colL,
  // and (wm|wn + i*16)>>1 is 0 mod 4, so the XOR term is (colL>>1)&3.
  const int rq = (quad ^ ((colL >> 1) & 3)) * 8;

  f32x4 acc[4][4];
  #pragma unroll
  for (int mi = 0; mi < 4; mi++)
    #pragma unroll
    for (int ni = 0; ni < 4; ni++)
      acc[mi][ni] = (f32x4){0.f, 0.f, 0.f, 0.f};

  // 4 gld16 per thread per K-tile (2 A chunks + 2 B chunks).
  auto stage_tile = [&](int t, int b) {
    const unsigned short* ga_ = ga + t * 32;
    const unsigned short* gb_ = gb + t * 32;
    unsigned short* la_ = la + b * 4096;
    unsigned short* lb_ = lb + b * 4096;
    gld16(ga_,             la_);
    gld16(ga_ + 16 * 1024, la_ + 512);
    gld16(gb_,             lb_);
    gld16(gb_ + 16 * 1024, lb_ + 512);
  };

  auto compute_tile = [&](int b) {
    bf16x8 af[4], bfr[4];
    #pragma unroll
    for (int i = 0; i < 4; i++) {
      af[i]  = *(const bf16x8*)(&As[b][wm + i * 16 + colL][rq]);
      bfr[i] = *(const bf16x8*)(&Bs[b][wn + i * 16 + colL][rq]);
    }
    __builtin_amdgcn_s_setprio(1);
    #pragma unroll
    for (int mi = 0; mi < 4; mi++)
      #pragma unroll
      for (int ni = 0; ni < 4; ni++)
        acc[mi][ni] = __builtin_amdgcn_mfma_f32_16x16x32_bf16(
            af[mi], bfr[ni], acc[mi][ni], 0, 0, 0);
    __builtin_amdgcn_s_setprio(0);
  };

  // prologue: tiles 0,1 in flight
  stage_tile(0, 0);
  stage_tile(1, 1);

  int buf = 0;
  for (int t = 0; t < 31; t++) {
    // own-wave tile-t loads done (tile t+1 may remain in flight: 4 loads)
    asm volatile("s_waitcnt vmcnt(4)" ::: "memory");
    // all waves have tile t staged; all waves done computing tile t-1,
    // so buf (t+2)%3 (= (t-1)%3) is free to overwrite.
    __builtin_amdgcn_s_barrier();
    if (t < 30) {
      int b2 = buf + 2; if (b2 >= 3) b2 -= 3;
      stage_tile(t + 2, b2);
    }
    compute_tile(buf);
    buf = (buf == 2) ? 0 : buf + 1;
  }
  asm volatile("s_waitcnt vmcnt(0)" ::: "memory");
  __builtin_amdgcn_s_barrier();
  compute_tile(buf);   // tile 31, buf 1

  // epilogue: tanh(enc + dec') * w_score, reduce over this wave's 64 n's,
  // store into slot (n-tile, wave-n-half) -- non-atomic.
  const int b = m0 >> 10;
  float decv[4], wsv[4];
  #pragma unroll
  for (int ni = 0; ni < 4; ni++) {
    int n = n0 + wn + ni * 16 + colL;
    decv[ni] = dec[b * 1024 + n];
    wsv[ni] = w_score[n];
  }
  const int slot = (swz & 7) * 2 + (wave & 1);
  #pragma unroll
  for (int mi = 0; mi < 4; mi++) {
    float rs[4] = {0.f, 0.f, 0.f, 0.f};
    #pragma unroll
    for (int ni = 0; ni < 4; ni++)
      #pragma unroll
      for (int r = 0; r < 4; r++)
        rs[r] += fast_tanh(acc[mi][ni][r] + decv[ni]) * wsv[ni];
    #pragma unroll
    for (int r = 0; r < 4; r++) {
      float v = rs[r];
      v += __shfl_xor(v, 1);
      v += __shfl_xor(v, 2);
      v += __shfl_xor(v, 4);
      v += __shfl_xor(v, 8);
      if (colL == 0)
        scores_p[slot * 65536 + m0 + wm + mi * 16 + quad * 4 + r] = v;
    }
  }
}

// ======== FALLBACK (ws too small): fused fp32-staging GEMM ====================
__global__ __launch_bounds__(256) void enc_score_f32_kernel(
    const float* __restrict__ A, const float* __restrict__ W,
    const float* __restrict__ dec, const float* __restrict__ w_score,
    float* __restrict__ scores_p) {
  __shared__ unsigned short As[128][32];
  __shared__ unsigned short Bs[128][32];
  const int bid = blockIdx.x;
  const int n0 = (bid & 7) * 128;
  const int m0 = (bid >> 3) * 128;
  const int tid = threadIdx.x;
  const int lane = tid & 63, wave = tid >> 6;
  const int wm = (wave >> 1) * 64, wn = (wave & 1) * 64;
  const int quad = lane >> 4, colL = lane & 15;
  const int srow = tid >> 3;
  const int scol = (tid & 7) * 4;
  f32x4 acc[4][4];
  #pragma unroll
  for (int mi = 0; mi < 4; mi++)
    #pragma unroll
    for (int ni = 0; ni < 4; ni++)
      acc[mi][ni] = (f32x4){0.f, 0.f, 0.f, 0.f};
  for (int k0 = 0; k0 < 1024; k0 += 32) {
    #pragma unroll
    for (int p = 0; p < 4; p++) {
      int r = p * 32 + srow;
      float4 va = *(const float4*)(A + (size_t)(m0 + r) * 1024 + (k0 + scol));
      float4 vb = *(const float4*)(W + (size_t)(n0 + r) * 1024 + (k0 + scol));
      ushort4 pa, pb;
      pa.x = f2bf(va.x); pa.y = f2bf(va.y); pa.z = f2bf(va.z); pa.w = f2bf(va.w);
      pb.x = f2bf(vb.x); pb.y = f2bf(vb.y); pb.z = f2bf(vb.z); pb.w = f2bf(vb.w);
      *(ushort4*)(&As[r][scol]) = pa;
      *(ushort4*)(&Bs[r][scol]) = pb;
    }
    __syncthreads();
    bf16x8 af[4], bfr[4];
    #pragma unroll
    for (int i = 0; i < 4; i++) {
      af[i]  = *(const bf16x8*)(&As[wm + i * 16 + colL][quad * 8]);
      bfr[i] = *(const bf16x8*)(&Bs[wn + i * 16 + colL][quad * 8]);
    }
    #pragma unroll
    for (int mi = 0; mi < 4; mi++)
      #pragma unroll
      for (int ni = 0; ni < 4; ni++)
        acc[mi][ni] = __builtin_amdgcn_mfma_f32_16x16x32_bf16(
            af[mi], bfr[ni], acc[mi][ni], 0, 0, 0);
    __syncthreads();
  }
  const int b = m0 >> 10;
  float decv[4], wsv[4];
  #pragma unroll
  for (int ni = 0; ni < 4; ni++) {
    int n = n0 + wn + ni * 16 + colL;
    decv[ni] = dec[b * 1024 + n];
    wsv[ni] = w_score[n];
  }
  const int slot = (bid & 7) * 2 + (wave & 1);
  #pragma unroll
  for (int mi = 0; mi < 4; mi++) {
    float rsv[4] = {0.f, 0.f, 0.f, 0.f};
    #pragma unroll
    for (int ni = 0; ni < 4; ni++)
      #pragma unroll
      for (int r = 0; r < 4; r++)
        rsv[r] += fast_tanh(acc[mi][ni][r] + decv[ni]) * wsv[ni];
    #pragma unroll
    for (int r = 0; r < 4; r++) {
      float v = rsv[r];
      v += __shfl_xor(v, 1);
      v += __shfl_xor(v, 2);
      v += __shfl_xor(v, 4);
      v += __shfl_xor(v, 8);
      if (colL == 0)
        scores_p[slot * 65536 + m0 + wm + mi * 16 + quad * 4 + r] = v;
    }
  }
}

// ------- softmax over T per batch; sums 16 partial slots; zeros context -------
__global__ void softmax_kernel(const float* __restrict__ scores_p,
                               float* __restrict__ weights,
                               float* __restrict__ context) {
  __shared__ float red[256];
  int b = blockIdx.x, tid = threadIdx.x;
  float4 z; z.x = z.y = z.z = z.w = 0.f;
  ((float4*)context)[blockIdx.x * 256 + tid] = z;
  float v[4];
  float mx = -1e30f;
  #pragma unroll
  for (int i = 0; i < 4; i++) {
    int m = b * 1024 + tid + i * 256;
    float s = 0.f;
    #pragma unroll
    for (int sl = 0; sl < 16; sl++) s += scores_p[sl * 65536 + m];
    v[i] = s;
    mx = fmaxf(mx, v[i]);
  }
  red[tid] = mx; __syncthreads();
  for (int off = 128; off > 0; off >>= 1) {
    if (tid < off) red[tid] = fmaxf(red[tid], red[tid + off]);
    __syncthreads();
  }
  mx = red[0]; __syncthreads();
  float sum = 0.f;
  #pragma unroll
  for (int i = 0; i < 4; i++) { v[i] = __expf(v[i] - mx); sum += v[i]; }
  red[tid] = sum; __syncthreads();
  for (int off = 128; off > 0; off >>= 1) {
    if (tid < off) red[tid] += red[tid + off];
    __syncthreads();
  }
  float inv = 1.0f / red[0];
  #pragma unroll
  for (int i = 0; i < 4; i++) weights[b * 1024 + tid + i * 256] = v[i] * inv;
}

// -------- context[b,h] = sum_t spatial[b,t,h] * weights[b,t]  (bf16 A) --------
__global__ void context_bf16_kernel(const unsigned short* __restrict__ Abf,
                                    const float* __restrict__ weights,
                                    float* __restrict__ context) {
  int b = blockIdx.x >> 3, tq = blockIdx.x & 7;
  int tid = threadIdx.x;
  __shared__ float wl[128];
  __shared__ float cs[128 * 8];
  if (tid < 128) wl[tid] = weights[b * 1024 + tq * 128 + tid];
  __syncthreads();
  const int hl = tid & 127, p = tid >> 7;   // 128 h-groups x 2 row parities
  const int h0 = hl * 8;
  const unsigned short* sp =
      Abf + ((size_t)(b * 1024 + tq * 128 + p)) * 1024 + h0;
  float acc[8];
  #pragma unroll
  for (int j = 0; j < 8; j++) acc[j] = 0.f;
  for (int t = 0; t < 128; t += 2) {
    float w = wl[t + p];
    ushort8 x = *(const ushort8*)(sp + (size_t)t * 1024);
    #pragma unroll
    for (int j = 0; j < 8; j++) acc[j] = fmaf(w, bf2f(x[j]), acc[j]);
  }
  if (p == 0) {
    #pragma unroll
    for (int j = 0; j < 8; j++) cs[hl * 8 + j] = acc[j];
  }
  __syncthreads();
  if (p == 1) {
    #pragma unroll
    for (int j = 0; j < 8; j++) cs[hl * 8 + j] += acc[j];
  }
  __syncthreads();
  if (p == 0) {
    #pragma unroll
    for (int j = 0; j < 8; j++)
      atomicAdd(&context[b * 1024 + h0 + j], cs[hl * 8 + j]);
  }
}

// fp32 context for fallback path
__global__ void context_f32_kernel(const float* __restrict__ spatial,
                                   const float* __restrict__ weights,
                                   float* __restrict__ context) {
  int b = blockIdx.x >> 3, tq = blockIdx.x & 7;
  int tid = threadIdx.x;
  __shared__ float wl[128];
  if (tid < 128) wl[tid] = weights[b * 1024 + tq * 128 + tid];
  __syncthreads();
  const float4* sp =
      (const float4*)(spatial + ((size_t)(b * 1024 + tq * 128)) * 1024);
  float4 acc; acc.x = acc.y = acc.z = acc.w = 0.f;
  #pragma unroll 4
  for (int t = 0; t < 128; t++) {
    float w = wl[t];
    float4 x = sp[(size_t)t * 256 + tid];
    acc.x = fmaf(w, x.x, acc.x);
    acc.y = fmaf(w, x.y, acc.y);
    acc.z = fmaf(w, x.z, acc.z);
    acc.w = fmaf(w, x.w, acc.w);
  }
  float* c = context + b * 1024 + tid * 4;
  atomicAdd(c + 0, acc.x);
  atomicAdd(c + 1, acc.y);
  atomicAdd(c + 2, acc.z);
  atomicAdd(c + 3, acc.w);
}

extern "C" void kernel_launch(void* const* d_in, const int* in_sizes, int n_in,
                              void* d_out, int out_size, void* d_ws, size_t ws_size,
                              hipStream_t stream) {
  const float* spatial  = (const float*)d_in[0];  // [64,1024,1024]
  const float* hidden   = (const float*)d_in[1];  // [64,1024]
  const float* W_enc    = (const float*)d_in[2];  // [1024,1024]
  const float* b_enc    = (const float*)d_in[3];  // [1024]
  const float* W_dec    = (const float*)d_in[4];  // [1024,1024]
  const float* b_dec    = (const float*)d_in[5];  // [1024]
  const float* w_score  = (const float*)d_in[6];  // [1024]
  // d_in[7] = b_score: softmax shift-invariant, unused.

  float* out      = (float*)d_out;
  float* context  = out;            // 65536 floats
  float* weights  = out + 65536;    // 65536 floats

  float* scores_p = (float*)d_ws;                            // 16*64K f32 @ 0
  float* dec      = scores_p + 16 * 65536;                   // 64K f32 @ 4MB
  unsigned short* Wbf = (unsigned short*)(dec + 65536);      // 1M  @ 4.25MB
  unsigned short* Abf = Wbf + 1024 * 1024;                   // 64M @ 6.25MB

  const size_t need =
      16ull * 65536 * 4 + 65536 * 4 + 2ull * 1024 * 1024 + 2ull * 65536 * 1024;

  if (ws_size >= need) {
    const int nCvt = 32 + 2048;   // W blocks + A blocks (8192 float4 each)
    prep_kernel<<<nCvt + 512, 256, 0, stream>>>(
        spatial, hidden, W_enc, b_enc, W_dec, b_dec, Wbf, Abf, dec, nCvt);
    enc_score_bf16_kernel<<<4096, 256, 0, stream>>>(Abf, Wbf, dec, w_score,
                                                    scores_p);
    softmax_kernel<<<64, 256, 0, stream>>>(scores_p, weights, context);
    context_bf16_kernel<<<512, 256, 0, stream>>>(Abf, weights, context);
  } else {
    prep_kernel<<<512, 256, 0, stream>>>(
        spatial, hidden, W_enc, b_enc, W_dec, b_dec, nullptr, nullptr, dec,
        0);
    enc_score_f32_kernel<<<4096, 256, 0, stream>>>(spatial, W_enc, dec,
                                                   w_score, scores_p);
    softmax_kernel<<<64, 256, 0, stream>>>(scores_p, weights, context);
    context_f32_kernel<<<512, 256, 0, stream>>>(spatial, weights, context);
  }
}

// Round 4
// 615.505 us; speedup vs baseline: 1.0895x; 1.0515x over previous
//
#include <hip/hip_runtime.h>
#include <hip/hip_bf16.h>
#include <math.h>

// Problem: B=64, T=1024, H=1024. M = B*T = 65536 score rows.
// out = [context (64*1024 fp32)] ++ [weights (64*1024 fp32)]
// ws fast path: [scores_p 16x64K f32 = 4MB][dec 256KB][W_bf16 2MB][A_bf16 128MB]

typedef __attribute__((ext_vector_type(8))) short bf16x8;
typedef __attribute__((ext_vector_type(8))) unsigned short ushort8;
typedef __attribute__((ext_vector_type(4))) float f32x4;

__device__ __forceinline__ unsigned short f2bf(float f) {
  union { float f; unsigned int u; } v; v.f = f;
  unsigned int r = v.u + 0x7FFFu + ((v.u >> 16) & 1u);  // RNE
  return (unsigned short)(r >> 16);
}

__device__ __forceinline__ float bf2f(unsigned short b) {
  union { unsigned int u; float f; } v; v.u = ((unsigned int)b) << 16;
  return v.f;
}

__device__ __forceinline__ float fast_tanh(float x) {
  float e = __expf(2.0f * x);
  return 1.0f - 2.0f / (e + 1.0f);  // saturates correctly at +-1
}

__device__ __forceinline__ void gld16(const void* g, void* l) {
  __builtin_amdgcn_global_load_lds(
      (const __attribute__((address_space(1))) void*)g,
      (__attribute__((address_space(3))) void*)l, 16, 0, 0);
}

// ===== fused prep kernel: W-cvt | A-cvt | dec-GEMV ============================
// cvt part grid-strided: 32 W-blocks + 2048 A-blocks, 32 float4/thread each.
__global__ __launch_bounds__(256) void prep_kernel(
    const float* __restrict__ spatial, const float* __restrict__ hidden,
    const float* __restrict__ W_enc, const float* __restrict__ b_enc,
    const float* __restrict__ W_dec, const float* __restrict__ b_dec,
    unsigned short* __restrict__ Wbf, unsigned short* __restrict__ Abf,
    float* __restrict__ dec, int nCvt) {
  __shared__ float hs[1024];
  const int bid = blockIdx.x, tid = threadIdx.x;
  if (bid < nCvt) {
    const bool isW = bid < 32;                 // W: 262144 float4 = 32 blocks
    const float* src = isW ? W_enc : spatial;  // A: 16M float4 = 2048 blocks
    unsigned short* dst = isW ? Wbf : Abf;
    const size_t base = (size_t)(isW ? bid : bid - 32) * 8192 + tid;
    #pragma unroll 4
    for (int i = 0; i < 32; i++) {
      size_t g4 = base + (size_t)i * 256;
      float4 v = ((const float4*)src)[g4];
      ushort4 o;
      o.x = f2bf(v.x); o.y = f2bf(v.y); o.z = f2bf(v.z); o.w = f2bf(v.w);
      *(ushort4*)(dst + g4 * 4) = o;
    }
    return;
  }
  const int dbid = bid - nCvt;                // 0..511
  const int b = dbid >> 3, o0 = (dbid & 7) * 128;
  const int wave = tid >> 6, lane = tid & 63;
  ((float4*)hs)[tid] = ((const float4*)(hidden + (size_t)b * 1024))[tid];
  __syncthreads();
  for (int it = 0; it < 32; it++) {
    int o = o0 + it * 4 + wave;
    const float4* w4 = (const float4*)(W_dec + (size_t)o * 1024);
    float4 acc; acc.x = acc.y = acc.z = acc.w = 0.f;
    #pragma unroll
    for (int j = 0; j < 4; j++) {
      int i = j * 64 + lane;
      float4 x = ((const float4*)hs)[i], y = w4[i];
      acc.x = fmaf(x.x, y.x, acc.x);
      acc.y = fmaf(x.y, y.y, acc.y);
      acc.z = fmaf(x.z, y.z, acc.z);
      acc.w = fmaf(x.w, y.w, acc.w);
    }
    float v = (acc.x + acc.y) + (acc.z + acc.w);
    #pragma unroll
    for (int off = 1; off < 64; off <<= 1) v += __shfl_xor(v, off);
    if (lane == 0) dec[b * 1024 + o] = v + b_dec[o] + b_enc[o];
  }
}

// ======== FAST PATH: 256x256 8-phase bf16 GEMM + tanh + w_score reduce ========
// m201-template port. C[m,n] = sum_k A[m,k]*W[n,k]. BM=BN=256, BK=64, 8 waves
// (2M x 4N), per-wave out 128x64 (acc[8][4] f32x4). LDS 128KB: As/Bs[2][256][64]
// double-buffered over K-tiles. Per K-tile: 4 phases x {ds_read quadrant frags,
// stage 1 half-tile (2 gld16), barrier, lgkm(0), setprio(1), 16 MFMA,
// setprio(0), barrier}. Counted vmcnt(4) ONCE per K-tile (phase 3) -- never a
// mid-loop drain.
//
// STAGE LEDGER (buf = kt&1; half-tile = 128 rows x 64 cols):
//   ph0: stage A-half0(kt+1) -> As[buf^1]   (last read kt-1 ph3, done)
//   ph1: stage A-half1(kt+1) -> As[buf^1]   (ditto)
//   ph2: stage B-half0(kt+2) -> Bs[buf]     (B of buf read only in ph0, done)
//   ph3: stage B-half1(kt+2) -> Bs[buf]     (ditto)
//   end-of-kt vmcnt(4): the 4 allowed-outstanding loads are exactly
//   B(kt+2) (issued ph2/ph3); everything older -- A(kt+1) issued ph0/ph1,
//   B(kt+1) issued during kt-1 -- is landed. Barrier publishes collectively
//   (every wave runs the same vmcnt on its own loads).
//   Tail: kt+1>=16 -> no A stage; kt+2>=16 -> no B stage and vmcnt(0)
//   (at kt=14 only A(15) is outstanding, so vmcnt(4) would be unsafe).
//
// T2 swizzle (rule 21, both-sides): LDS row slot c (16B units, 8/row) holds
// global slot c ^ (row&7). Stage: row&7 == lane>>3 (row0 of every gld16 region
// is 0 mod 8), so src col = ((lane&7) ^ (lane>>3))*8. Read: row&7 == colL&7
// (wm/wn/mi*16/ni*16 all 0 mod 8), so slot = (s*4+quad) ^ (colL&7). Spreads a
// b128 frag read over all 8 slots (8 lanes/slot = HW minimum for 128B rows).
// T1 XCD swizzle: grid 1024 = 8*128, bijective.
__global__ __launch_bounds__(512, 2) void enc_score_bf16_kernel(
    const unsigned short* __restrict__ A,   // bf16 bits [65536,1024]
    const unsigned short* __restrict__ W,   // bf16 bits [1024,1024]
    const float* __restrict__ dec,          // [64,1024] (b_dec+b_enc folded)
    const float* __restrict__ w_score,
    float* __restrict__ scores_p)           // [16][65536]
{
  __shared__ unsigned short As[2][256][64];   // 64 KB
  __shared__ unsigned short Bs[2][256][64];   // 64 KB

  const int bid = blockIdx.x;                 // 1024 blocks
  const int swz = (bid & 7) * 128 + (bid >> 3);
  const int nt = swz & 3;                     // 4 n-tiles
  const int m0 = (swz >> 2) * 256;
  const int n0 = nt * 256;
  const int tid = threadIdx.x;
  const int lane = tid & 63, wave = tid >> 6; // 8 waves
  const int wm = (wave >> 2) * 128;           // 0 / 128
  const int wn = (wave & 3) * 64;             // 0,64,128,192
  const int quad = lane >> 4, colL = lane & 15;

  // staging: wave covers rows [wave*16 + j*8, +8) of a half-tile per gld16;
  // lane l -> row +(l>>3), src col pre-swizzled ((l&7)^(l>>3))*8.
  const int s_rowoff = wave * 16 + (lane >> 3);
  const int s_col = ((lane & 7) ^ (lane >> 3)) * 8;
  const unsigned short* gA = A + (size_t)m0 * 1024;
  const unsigned short* gB = W + (size_t)n0 * 1024;

  auto stageA = [&](int kt, int h) {
    const unsigned short* src =
        gA + (size_t)(h * 128 + s_rowoff) * 1024 + kt * 64 + s_col;
    unsigned short* dst = &As[kt & 1][h * 128 + wave * 16][0];
    gld16(src, dst);
    gld16(src + 8 * 1024, dst + 8 * 64);
  };
  auto stageB = [&](int kt, int h) {
    const unsigned short* src =
        gB + (size_t)(h * 128 + s_rowoff) * 1024 + kt * 64 + s_col;
    unsigned short* dst = &Bs[kt & 1][h * 128 + wave * 16][0];
    gld16(src, dst);
    gld16(src + 8 * 1024, dst + 8 * 64);
  };

  // fragment-read swizzled col slots for kstep s=0,1 (elements)
  const int xs0 = ((0 * 4 + quad) ^ (colL & 7)) * 8;
  const int xs1 = ((1 * 4 + quad) ^ (colL & 7)) * 8;

  f32x4 acc[8][4];
  #pragma unroll
  for (int mi = 0; mi < 8; mi++)
    #pragma unroll
    for (int ni = 0; ni < 4; ni++)
      acc[mi][ni] = (f32x4){0.f, 0.f, 0.f, 0.f};

  // prologue: K-tile 0 fully + B halves of K-tile 1 (12 loads/thread);
  // allow B(1)'s 4 to remain in flight.
  stageA(0, 0); stageA(0, 1); stageB(0, 0); stageB(0, 1);
  stageB(1, 0); stageB(1, 1);
  asm volatile("s_waitcnt vmcnt(4)" ::: "memory");
  __builtin_amdgcn_s_barrier();

  auto ktile = [&](int kt, int buf) {
    bf16x8 bfr[4][2];
    #pragma unroll
    for (int q = 0; q < 4; q++) {
      bf16x8 af[2][2];
      #pragma unroll
      for (int mj = 0; mj < 2; mj++) {
        const int row = wm + (q * 2 + mj) * 16 + colL;
        af[mj][0] = *(const bf16x8*)&As[buf][row][xs0];
        af[mj][1] = *(const bf16x8*)&As[buf][row][xs1];
      }
      if (q == 0) {
        #pragma unroll
        for (int ni = 0; ni < 4; ni++) {
          const int row = wn + ni * 16 + colL;
          bfr[ni][0] = *(const bf16x8*)&Bs[buf][row][xs0];
          bfr[ni][1] = *(const bf16x8*)&Bs[buf][row][xs1];
        }
      }
      if (q == 0 && kt + 1 < 16) stageA(kt + 1, 0);
      if (q == 1 && kt + 1 < 16) stageA(kt + 1, 1);
      if (q == 2 && kt + 2 < 16) stageB(kt + 2, 0);
      if (q == 3 && kt + 2 < 16) stageB(kt + 2, 1);
      __builtin_amdgcn_s_barrier();
      asm volatile("s_waitcnt lgkmcnt(0)" ::: "memory");
      __builtin_amdgcn_s_setprio(1);
      #pragma unroll
      for (int s = 0; s < 2; s++)
        #pragma unroll
        for (int mj = 0; mj < 2; mj++)
          #pragma unroll
          for (int ni = 0; ni < 4; ni++)
            acc[q * 2 + mj][ni] = __builtin_amdgcn_mfma_f32_16x16x32_bf16(
                af[mj][s], bfr[ni][s], acc[q * 2 + mj][ni], 0, 0, 0);
      __builtin_amdgcn_s_setprio(0);
      if (q == 3) {
        if (kt + 2 < 16) asm volatile("s_waitcnt vmcnt(4)" ::: "memory");
        else             asm volatile("s_waitcnt vmcnt(0)" ::: "memory");
      }
      __builtin_amdgcn_s_barrier();
    }
  };

  for (int ku = 0; ku < 16; ku += 2) {
    ktile(ku, 0);
    ktile(ku + 1, 1);
  }

  // epilogue: tanh(enc + dec') * w_score, reduce over this wave's 64 n's,
  // store into slot (n-tile, wave-n-col) -- non-atomic, all 16 slots written.
  const int b = m0 >> 10;
  float decv[4], wsv[4];
  #pragma unroll
  for (int ni = 0; ni < 4; ni++) {
    int n = n0 + wn + ni * 16 + colL;
    decv[ni] = dec[b * 1024 + n];
    wsv[ni] = w_score[n];
  }
  const int slot = nt * 4 + (wave & 3);
  #pragma unroll
  for (int mi = 0; mi < 8; mi++) {
    float rs[4] = {0.f, 0.f, 0.f, 0.f};
    #pragma unroll
    for (int ni = 0; ni < 4; ni++)
      #pragma unroll
      for (int r = 0; r < 4; r++)
        rs[r] += fast_tanh(acc[mi][ni][r] + decv[ni]) * wsv[ni];
    #pragma unroll
    for (int r = 0; r < 4; r++) {
      float v = rs[r];
      v += __shfl_xor(v, 1);
      v += __shfl_xor(v, 2);
      v += __shfl_xor(v, 4);
      v += __shfl_xor(v, 8);
      if (colL == 0)
        scores_p[slot * 65536 + m0 + wm + mi * 16 + quad * 4 + r] = v;
    }
  }
}

// ======== FALLBACK (ws too small): fused fp32-staging GEMM ====================
__global__ __launch_bounds__(256) void enc_score_f32_kernel(
    const float* __restrict__ A, const float* __restrict__ W,
    const float* __restrict__ dec, const float* __restrict__ w_score,
    float* __restrict__ scores_p) {
  __shared__ unsigned short As[128][32];
  __shared__ unsigned short Bs[128][32];
  const int bid = blockIdx.x;
  const int n0 = (bid & 7) * 128;
  const int m0 = (bid >> 3) * 128;
  const int tid = threadIdx.x;
  const int lane = tid & 63, wave = tid >> 6;
  const int wm = (wave >> 1) * 64, wn = (wave & 1) * 64;
  const int quad = lane >> 4, colL = lane & 15;
  const int srow = tid >> 3;
  const int scol = (tid & 7) * 4;
  f32x4 acc[4][4];
  #pragma unroll
  for (int mi = 0; mi < 4; mi++)
    #pragma unroll
    for (int ni = 0; ni < 4; ni++)
      acc[mi][ni] = (f32x4){0.f, 0.f, 0.f, 0.f};
  for (int k0 = 0; k0 < 1024; k0 += 32) {
    #pragma unroll
    for (int p = 0; p < 4; p++) {
      int r = p * 32 + srow;
      float4 va = *(const float4*)(A + (size_t)(m0 + r) * 1024 + (k0 + scol));
      float4 vb = *(const float4*)(W + (size_t)(n0 + r) * 1024 + (k0 + scol));
      ushort4 pa, pb;
      pa.x = f2bf(va.x); pa.y = f2bf(va.y); pa.z = f2bf(va.z); pa.w = f2bf(va.w);
      pb.x = f2bf(vb.x); pb.y = f2bf(vb.y); pb.z = f2bf(vb.z); pb.w = f2bf(vb.w);
      *(ushort4*)(&As[r][scol]) = pa;
      *(ushort4*)(&Bs[r][scol]) = pb;
    }
    __syncthreads();
    bf16x8 af[4], bfr[4];
    #pragma unroll
    for (int i = 0; i < 4; i++) {
      af[i]  = *(const bf16x8*)(&As[wm + i * 16 + colL][quad * 8]);
      bfr[i] = *(const bf16x8*)(&Bs[wn + i * 16 + colL][quad * 8]);
    }
    #pragma unroll
    for (int mi = 0; mi < 4; mi++)
      #pragma unroll
      for (int ni = 0; ni < 4; ni++)
        acc[mi][ni] = __builtin_amdgcn_mfma_f32_16x16x32_bf16(
            af[mi], bfr[ni], acc[mi][ni], 0, 0, 0);
    __syncthreads();
  }
  const int b = m0 >> 10;
  float decv[4], wsv[4];
  #pragma unroll
  for (int ni = 0; ni < 4; ni++) {
    int n = n0 + wn + ni * 16 + colL;
    decv[ni] = dec[b * 1024 + n];
    wsv[ni] = w_score[n];
  }
  const int slot = (bid & 7) * 2 + (wave & 1);
  #pragma unroll
  for (int mi = 0; mi < 4; mi++) {
    float rsv[4] = {0.f, 0.f, 0.f, 0.f};
    #pragma unroll
    for (int ni = 0; ni < 4; ni++)
      #pragma unroll
      for (int r = 0; r < 4; r++)
        rsv[r] += fast_tanh(acc[mi][ni][r] + decv[ni]) * wsv[ni];
    #pragma unroll
    for (int r = 0; r < 4; r++) {
      float v = rsv[r];
      v += __shfl_xor(v, 1);
      v += __shfl_xor(v, 2);
      v += __shfl_xor(v, 4);
      v += __shfl_xor(v, 8);
      if (colL == 0)
        scores_p[slot * 65536 + m0 + wm + mi * 16 + quad * 4 + r] = v;
    }
  }
}

// ------- softmax over T per batch; sums 16 partial slots; zeros context -------
__global__ void softmax_kernel(const float* __restrict__ scores_p,
                               float* __restrict__ weights,
                               float* __restrict__ context) {
  __shared__ float red[256];
  int b = blockIdx.x, tid = threadIdx.x;
  float4 z; z.x = z.y = z.z = z.w = 0.f;
  ((float4*)context)[blockIdx.x * 256 + tid] = z;
  float v[4];
  float mx = -1e30f;
  #pragma unroll
  for (int i = 0; i < 4; i++) {
    int m = b * 1024 + tid + i * 256;
    float s = 0.f;
    #pragma unroll
    for (int sl = 0; sl < 16; sl++) s += scores_p[sl * 65536 + m];
    v[i] = s;
    mx = fmaxf(mx, v[i]);
  }
  red[tid] = mx; __syncthreads();
  for (int off = 128; off > 0; off >>= 1) {
    if (tid < off) red[tid] = fmaxf(red[tid], red[tid + off]);
    __syncthreads();
  }
  mx = red[0]; __syncthreads();
  float sum = 0.f;
  #pragma unroll
  for (int i = 0; i < 4; i++) { v[i] = __expf(v[i] - mx); sum += v[i]; }
  red[tid] = sum; __syncthreads();
  for (int off = 128; off > 0; off >>= 1) {
    if (tid < off) red[tid] += red[tid + off];
    __syncthreads();
  }
  float inv = 1.0f / red[0];
  #pragma unroll
  for (int i = 0; i < 4; i++) weights[b * 1024 + tid + i * 256] = v[i] * inv;
}

// -------- context[b,h] = sum_t spatial[b,t,h] * weights[b,t]  (bf16 A) --------
__global__ void context_bf16_kernel(const unsigned short* __restrict__ Abf,
                                    const float* __restrict__ weights,
                                    float* __restrict__ context) {
  int b = blockIdx.x >> 3, tq = blockIdx.x & 7;
  int tid = threadIdx.x;
  __shared__ float wl[128];
  __shared__ float cs[128 * 8];
  if (tid < 128) wl[tid] = weights[b * 1024 + tq * 128 + tid];
  __syncthreads();
  const int hl = tid & 127, p = tid >> 7;   // 128 h-groups x 2 row parities
  const int h0 = hl * 8;
  const unsigned short* sp =
      Abf + ((size_t)(b * 1024 + tq * 128 + p)) * 1024 + h0;
  float acc[8];
  #pragma unroll
  for (int j = 0; j < 8; j++) acc[j] = 0.f;
  for (int t = 0; t < 128; t += 2) {
    float w = wl[t + p];
    ushort8 x = *(const ushort8*)(sp + (size_t)t * 1024);
    #pragma unroll
    for (int j = 0; j < 8; j++) acc[j] = fmaf(w, bf2f(x[j]), acc[j]);
  }
  if (p == 0) {
    #pragma unroll
    for (int j = 0; j < 8; j++) cs[hl * 8 + j] = acc[j];
  }
  __syncthreads();
  if (p == 1) {
    #pragma unroll
    for (int j = 0; j < 8; j++) cs[hl * 8 + j] += acc[j];
  }
  __syncthreads();
  if (p == 0) {
    #pragma unroll
    for (int j = 0; j < 8; j++)
      atomicAdd(&context[b * 1024 + h0 + j], cs[hl * 8 + j]);
  }
}

// fp32 context for fallback path
__global__ void context_f32_kernel(const float* __restrict__ spatial,
                                   const float* __restrict__ weights,
                                   float* __restrict__ context) {
  int b = blockIdx.x >> 3, tq = blockIdx.x & 7;
  int tid = threadIdx.x;
  __shared__ float wl[128];
  if (tid < 128) wl[tid] = weights[b * 1024 + tq * 128 + tid];
  __syncthreads();
  const float4* sp =
      (const float4*)(spatial + ((size_t)(b * 1024 + tq * 128)) * 1024);
  float4 acc; acc.x = acc.y = acc.z = acc.w = 0.f;
  #pragma unroll 4
  for (int t = 0; t < 128; t++) {
    float w = wl[t];
    float4 x = sp[(size_t)t * 256 + tid];
    acc.x = fmaf(w, x.x, acc.x);
    acc.y = fmaf(w, x.y, acc.y);
    acc.z = fmaf(w, x.z, acc.z);
    acc.w = fmaf(w, x.w, acc.w);
  }
  float* c = context + b * 1024 + tid * 4;
  atomicAdd(c + 0, acc.x);
  atomicAdd(c + 1, acc.y);
  atomicAdd(c + 2, acc.z);
  atomicAdd(c + 3, acc.w);
}

extern "C" void kernel_launch(void* const* d_in, const int* in_sizes, int n_in,
                              void* d_out, int out_size, void* d_ws, size_t ws_size,
                              hipStream_t stream) {
  const float* spatial  = (const float*)d_in[0];  // [64,1024,1024]
  const float* hidden   = (const float*)d_in[1];  // [64,1024]
  const float* W_enc    = (const float*)d_in[2];  // [1024,1024]
  const float* b_enc    = (const float*)d_in[3];  // [1024]
  const float* W_dec    = (const float*)d_in[4];  // [1024,1024]
  const float* b_dec    = (const float*)d_in[5];  // [1024]
  const float* w_score  = (const float*)d_in[6];  // [1024]
  // d_in[7] = b_score: softmax shift-invariant, unused.

  float* out      = (float*)d_out;
  float* context  = out;            // 65536 floats
  float* weights  = out + 65536;    // 65536 floats

  float* scores_p = (float*)d_ws;                            // 16*64K f32 @ 0
  float* dec      = scores_p + 16 * 65536;                   // 64K f32 @ 4MB
  unsigned short* Wbf = (unsigned short*)(dec + 65536);      // 1M  @ 4.25MB
  unsigned short* Abf = Wbf + 1024 * 1024;                   // 64M @ 6.25MB

  const size_t need =
      16ull * 65536 * 4 + 65536 * 4 + 2ull * 1024 * 1024 + 2ull * 65536 * 1024;

  if (ws_size >= need) {
    const int nCvt = 32 + 2048;   // W blocks + A blocks (8192 float4 each)
    prep_kernel<<<nCvt + 512, 256, 0, stream>>>(
        spatial, hidden, W_enc, b_enc, W_dec, b_dec, Wbf, Abf, dec, nCvt);
    enc_score_bf16_kernel<<<1024, 512, 0, stream>>>(Abf, Wbf, dec, w_score,
                                                    scores_p);
    softmax_kernel<<<64, 256, 0, stream>>>(scores_p, weights, context);
    context_bf16_kernel<<<512, 256, 0, stream>>>(Abf, weights, context);
  } else {
    prep_kernel<<<512, 256, 0, stream>>>(
        spatial, hidden, W_enc, b_enc, W_dec, b_dec, nullptr, nullptr, dec,
        0);
    enc_score_f32_kernel<<<4096, 256, 0, stream>>>(spatial, W_enc, dec,
                                                   w_score, scores_p);
    softmax_kernel<<<64, 256, 0, stream>>>(scores_p, weights, context);
    context_f32_kernel<<<512, 256, 0, stream>>>(spatial, weights, context);
  }
}